// Round 11
// baseline (366.828 us; speedup 1.0000x reference)
//
#include <hip/hip_runtime.h>
#include <stdint.h>
#include <stddef.h>

#define HN   12
#define SN   2048
#define EN   768
#define DKN  64
#define BATCH 4
#define MROWS 8192   // BATCH*SN

typedef short bf16x8 __attribute__((ext_vector_type(8)));
typedef float f32x4 __attribute__((ext_vector_type(4)));

__device__ __forceinline__ unsigned short f2bf(float f) {
  union { float f; unsigned u; } x; x.f = f;
  unsigned r = x.u + 0x7fffu + ((x.u >> 16) & 1u);
  return (unsigned short)(r >> 16);
}

#if __has_builtin(__builtin_amdgcn_cvt_pk_bf16_f32)
typedef __bf16 bf16v2 __attribute__((ext_vector_type(2)));
__device__ __forceinline__ unsigned pk_bf16(float a, float b) {
  union { bf16v2 v; unsigned u; } c;
  c.v = __builtin_amdgcn_cvt_pk_bf16_f32(a, b);
  return c.u;
}
#else
__device__ __forceinline__ unsigned pk_bf16(float a, float b) {
  return (unsigned)f2bf(a) | ((unsigned)f2bf(b) << 16);
}
#endif

// byte-pair expand via v_perm: sel 0x01010000 -> [b0 b0 b1 b1], sel 0x03030202 -> [b2 b2 b3 b3].
#if __has_builtin(__builtin_amdgcn_perm)
__device__ __forceinline__ unsigned pmexp(unsigned m, unsigned sel) {
  return __builtin_amdgcn_perm(m, m, sel);
}
#else
__device__ __forceinline__ unsigned pmexp(unsigned m, unsigned sel) {
  const unsigned b0 = (m >> (8 * (sel & 3))) & 0xFFu;
  const unsigned b1 = (m >> (8 * ((sel >> 16) & 3))) & 0xFFu;
  return (b0 ? 0xFFFFu : 0u) | (b1 ? 0xFFFF0000u : 0u);
}
#endif

#define GLD_LDS16(gptr, lptr) \
  __builtin_amdgcn_global_load_lds((const __attribute__((address_space(1))) void*)(gptr), \
                                   (__attribute__((address_space(3))) void*)(lptr), 16, 0, 0)

// ---------------------------------------------------------------- fused f32->bf16 + mask->keep-bytes
#define NBIG4 1572864   // NBIG/4
#define NW4   147456    // NW/4
#define NCVTB 20736     // (3*NBIG4 + 4*NW4)/256
#define NMASKB 16384    // B*S*S/4/256
__global__ __launch_bounds__(256) void cvt_mask(const float* __restrict__ q,
                                                const float* __restrict__ k,
                                                const float* __restrict__ v,
                                                const float* __restrict__ wq,
                                                const float* __restrict__ wk,
                                                const float* __restrict__ wv,
                                                const float* __restrict__ wo,
                                                unsigned short* __restrict__ dst,
                                                const int* __restrict__ mask,
                                                unsigned* __restrict__ mout) {
  if (blockIdx.x < NCVTB) {
    const int i = blockIdx.x * 256 + threadIdx.x;
    const float* src;
    int off;
    if (i < 3 * NBIG4) {
      const int r = i / NBIG4;
      src = (r == 0) ? q : (r == 1) ? k : v;
      off = i - r * NBIG4;
    } else {
      const int j = i - 3 * NBIG4;
      const int r = j / NW4;
      src = (r == 0) ? wq : (r == 1) ? wk : (r == 2) ? wv : wo;
      off = j - r * NW4;
    }
    float4 val = ((const float4*)src)[off];
    ushort4 o;
    o.x = f2bf(val.x); o.y = f2bf(val.y); o.z = f2bf(val.z); o.w = f2bf(val.w);
    ((ushort4*)dst)[i] = o;
  } else {
    // keep = (mask==0) -> 0xFF ; exclude -> 0x00.  u32 packs 4 consecutive keys.
    const size_t i = (size_t)(blockIdx.x - NCVTB) * 256 + threadIdx.x;
    const int4 m = ((const int4*)mask)[i];
    unsigned o = (m.x ? 0u : 0xFFu) | (m.y ? 0u : 0xFF00u) |
                 (m.z ? 0u : 0xFF0000u) | (m.w ? 0u : 0xFF000000u);
    mout[i] = o;
  }
}

// ---------------------------------------------------------------- batched QKV GEMM (R4 BM=128 exact)
// z=0: Q (scaled, [B,H,S,DK]); z=1: K ([B,H,S,DK]); z=2: V transposed ([B,H,DK,S])
__global__ __launch_bounds__(256) void gemm_qkv(const unsigned short* __restrict__ Xb,
                                                const unsigned short* __restrict__ Wb,
                                                unsigned short* __restrict__ Ob,
                                                float qscale) {
  __shared__ unsigned short As[128 * 32];
  __shared__ unsigned short Bs[128 * 32];
  const int tid  = threadIdx.x;
  const int wave = tid >> 6;
  const int lane = tid & 63;
  const int quad = lane >> 4;
  const int l16  = lane & 15;
  const int bm = blockIdx.x;
  const int bn = blockIdx.y;
  const int z  = blockIdx.z;
  const int wm = wave & 1;
  const int wn = wave >> 1;

  const unsigned short* X = Xb + (size_t)z * MROWS * EN;
  const unsigned short* W = Wb + (size_t)z * EN * EN;
  unsigned short* O = Ob + (size_t)z * MROWS * EN;

  f32x4 acc[4][4] = {};
  const int srow = lane >> 2;
  const int schk = lane & 3;

  for (int bk = 0; bk < 24; ++bk) {
    __syncthreads();
#pragma unroll
    for (int r = 0; r < 2; ++r) {
      const int rowblk = r * 64 + wave * 16;
      GLD_LDS16(X + (size_t)(bm * 128 + rowblk + srow) * EN + bk * 32 + schk * 8,
                As + rowblk * 32);
      GLD_LDS16(W + (size_t)(bn * 128 + rowblk + srow) * EN + bk * 32 + schk * 8,
                Bs + rowblk * 32);
    }
    __syncthreads();

    bf16x8 af[4], bfr[4];
#pragma unroll
    for (int mt = 0; mt < 4; ++mt)
      af[mt] = *(const bf16x8*)&As[(wm * 64 + mt * 16 + l16) * 32 + quad * 8];
#pragma unroll
    for (int nt = 0; nt < 4; ++nt)
      bfr[nt] = *(const bf16x8*)&Bs[(wn * 64 + nt * 16 + l16) * 32 + quad * 8];
#pragma unroll
    for (int mt = 0; mt < 4; ++mt)
#pragma unroll
      for (int nt = 0; nt < 4; ++nt)
        acc[mt][nt] = __builtin_amdgcn_mfma_f32_16x16x32_bf16(af[mt], bfr[nt], acc[mt][nt], 0, 0, 0);
  }

  const int m0 = bm * 128 + wm * 64;
  const int n0 = bn * 128 + wn * 64;
  const float scale = (z == 0) ? qscale : 1.0f;

  if (z < 2) {
#pragma unroll
    for (int mt = 0; mt < 4; ++mt) {
#pragma unroll
      for (int nt = 0; nt < 4; ++nt) {
        const int n = n0 + nt * 16 + l16;
        const int h = n >> 6, d = n & 63;
#pragma unroll
        for (int r = 0; r < 4; ++r) {
          const int m = m0 + mt * 16 + quad * 4 + r;
          const int b = m >> 11, s = m & 2047;
          O[((size_t)(b * HN + h) * SN + s) * DKN + d] = f2bf(acc[mt][nt][r] * scale);
        }
      }
    }
  } else {
#pragma unroll
    for (int mt = 0; mt < 4; ++mt) {
#pragma unroll
      for (int nt = 0; nt < 4; ++nt) {
        const int n = n0 + nt * 16 + l16;
        const int h = n >> 6, d = n & 63;
        const int m = m0 + mt * 16 + quad * 4;
        const int b = m >> 11, s = m & 2047;
        ushort4 pk;
        pk.x = f2bf(acc[mt][nt][0]);
        pk.y = f2bf(acc[mt][nt][1]);
        pk.z = f2bf(acc[mt][nt][2]);
        pk.w = f2bf(acc[mt][nt][3]);
        *(ushort4*)&O[((size_t)(b * HN + h) * DKN + d) * SN + s] = pk;
      }
    }
  }
}

// ---------------------------------------------------------------- GEMM  C = X @ W^T + residual (R4 BM=128 exact)
__global__ __launch_bounds__(256) void gemm_out(const unsigned short* __restrict__ X,
                                                const unsigned short* __restrict__ W,
                                                float* __restrict__ O,
                                                const float* __restrict__ residual) {
  __shared__ unsigned short As[128 * 32];
  __shared__ unsigned short Bs[128 * 32];
  const int tid  = threadIdx.x;
  const int wave = tid >> 6;
  const int lane = tid & 63;
  const int quad = lane >> 4;
  const int l16  = lane & 15;
  const int bm = blockIdx.x;
  const int bn = blockIdx.y;
  const int wm = wave & 1;
  const int wn = wave >> 1;

  f32x4 acc[4][4] = {};
  const int srow = lane >> 2;
  const int schk = lane & 3;

  for (int bk = 0; bk < 24; ++bk) {
    __syncthreads();
#pragma unroll
    for (int r = 0; r < 2; ++r) {
      const int rowblk = r * 64 + wave * 16;
      GLD_LDS16(X + (size_t)(bm * 128 + rowblk + srow) * EN + bk * 32 + schk * 8,
                As + rowblk * 32);
      GLD_LDS16(W + (size_t)(bn * 128 + rowblk + srow) * EN + bk * 32 + schk * 8,
                Bs + rowblk * 32);
    }
    __syncthreads();

    bf16x8 af[4], bfr[4];
#pragma unroll
    for (int mt = 0; mt < 4; ++mt)
      af[mt] = *(const bf16x8*)&As[(wm * 64 + mt * 16 + l16) * 32 + quad * 8];
#pragma unroll
    for (int nt = 0; nt < 4; ++nt)
      bfr[nt] = *(const bf16x8*)&Bs[(wn * 64 + nt * 16 + l16) * 32 + quad * 8];
#pragma unroll
    for (int mt = 0; mt < 4; ++mt)
#pragma unroll
      for (int nt = 0; nt < 4; ++nt)
        acc[mt][nt] = __builtin_amdgcn_mfma_f32_16x16x32_bf16(af[mt], bfr[nt], acc[mt][nt], 0, 0, 0);
  }

  const int m0 = bm * 128 + wm * 64;
  const int n0 = bn * 128 + wn * 64;
#pragma unroll
  for (int mt = 0; mt < 4; ++mt) {
#pragma unroll
    for (int nt = 0; nt < 4; ++nt) {
      const int n = n0 + nt * 16 + l16;
#pragma unroll
      for (int r = 0; r < 4; ++r) {
        const int m = m0 + mt * 16 + quad * 4 + r;
        const size_t idx = (size_t)m * EN + n;
        O[idx] = acc[mt][nt][r] + residual[idx];
      }
    }
  }
}

// ---------------------------------------------------------------- flash attention (key-split waves)
// R10 kernel (XCD swizzle kept: FETCH 115->58MB, -4us) + LDS cut to 16384B.
// Occupancy was capped at ~3 blocks/CU, consistent with a 64KB LDS pool / 17920B.
// Combine restructured to TWO passes (ph = qhalf) through a [32][68] buffer with
// lpart folded into the same 16KB LDSBUF -> total __shared__ = 16384 -> 4 blocks/CU.
// kt loop / staging / mask / exp2 path byte-identical to R10.
__global__ __launch_bounds__(256, 4) void attn_kernel(const unsigned short* __restrict__ Q,
                                                      const unsigned short* __restrict__ K,
                                                      const unsigned short* __restrict__ Vt,
                                                      const unsigned char* __restrict__ Mb,
                                                      unsigned short* __restrict__ Ctx) {
  __shared__ __align__(16) unsigned char LDSBUF[16384];   // staging (16KB) / combine (8704+128B)
  unsigned short* Ks = (unsigned short*)LDSBUF;           // [64][64] perm-key x d
  unsigned short* Vs = (unsigned short*)(LDSBUF + 8192);  // [64][64] d x key
  float* Cmb = (float*)LDSBUF;                            // [32][68] q x d, padded (combine)
  float* lp  = (float*)(LDSBUF + 8704);                   // [2][16] l partials (combine)

  const int tid  = threadIdx.x;
  const int wave = tid >> 6, lane = tid & 63;
  const int quad = lane >> 4, l16 = lane & 15;
  const int qhalf = wave >> 1, kh = wave & 1;

  // XCD-aware swizzle: 1536 blocks, 8 XCDs, 192 per XCD; qt fast within a head.
  const int wg = blockIdx.x;
  const int sw = (wg & 7) * 192 + (wg >> 3);
  const int qt = sw & 31;
  const int bh = sw >> 5;
  const int b = bh / HN, h = bh - b * HN;

  const unsigned short* Qp = Q + (size_t)bh * SN * DKN;
  const unsigned short* Kp = K + (size_t)bh * SN * DKN;
  const unsigned short* Vp = Vt + (size_t)bh * DKN * SN;

  const int srow = lane >> 3;
  const int schk = lane & 7;
  const int swsrc = (schk ^ srow) * 8;
  const int c0 = (quad ^ (l16 & 7)) * 8;                    // K frag chunks (d)
  const int cv = (((kh << 2) + quad) ^ (l16 & 7)) * 8;      // V frag chunk (key half kh)

  // K staging: dest physical row (within half) pw holds logical key yk
  const int pw = wave * 8 + srow;
  const int yk = (((pw >> 2) & 3) << 3) + ((pw >> 4) << 2) + (pw & 3);

  // Q B-fragments for this wave's 32 q-rows (2 groups of 16), hoisted
  bf16x8 bq[2][2];
#pragma unroll
  for (int qg = 0; qg < 2; ++qg) {
    const int R = qt * 64 + qhalf * 32 + qg * 16 + l16;
    bq[qg][0] = *(const bf16x8*)(Qp + (size_t)R * DKN + quad * 8);
    bq[qg][1] = *(const bf16x8*)(Qp + (size_t)R * DKN + 32 + quad * 8);
  }

  // keep-byte mask pointers: row*SN + kt*64 + kh*32 + quad*8 (8B-aligned); qg=1 at +16 rows
  const unsigned char* Ml0 =
      Mb + ((size_t)b * SN + (size_t)(qt * 64 + qhalf * 32 + l16)) * SN + kh * 32 + quad * 8;
  const unsigned char* Ml1 = Ml0 + (size_t)16 * SN;

  f32x4 o_acc[2][4] = {};
  f32x4 o_l[2] = {};
  bf16x8 ones;
#pragma unroll
  for (int i = 0; i < 8; ++i) ones[i] = (short)0x3F80;  // bf16 1.0

  for (int kt = 0; kt < 32; ++kt) {
    __syncthreads();
    GLD_LDS16(Kp + (size_t)(kt * 64 + yk) * DKN + swsrc,              Ks + (wave * 8) * 64);
    GLD_LDS16(Kp + (size_t)(kt * 64 + 32 + yk) * DKN + swsrc,         Ks + (32 + wave * 8) * 64);
    GLD_LDS16(Vp + (size_t)(wave * 8 + srow) * SN + kt * 64 + swsrc,      Vs + (wave * 8) * 64);
    GLD_LDS16(Vp + (size_t)(32 + wave * 8 + srow) * SN + kt * 64 + swsrc, Vs + (32 + wave * 8) * 64);
    const uint2 mbv0 = *(const uint2*)(Ml0 + (size_t)kt * 64);
    const uint2 mbv1 = *(const uint2*)(Ml1 + (size_t)kt * 64);
    __syncthreads();

    // K fragments: this wave's key-half only
    bf16x8 ak[2][2];
#pragma unroll
    for (int mt = 0; mt < 2; ++mt) {
      const int base = (kh * 32 + mt * 16 + l16) * 64;
      ak[mt][0] = *(const bf16x8*)&Ks[base + c0];
      ak[mt][1] = *(const bf16x8*)&Ks[base + (c0 ^ 32)];
    }

    // S^T = K x Q^T for 32q x 32k
    f32x4 st[2][2];
#pragma unroll
    for (int qg = 0; qg < 2; ++qg)
#pragma unroll
      for (int mt = 0; mt < 2; ++mt) {
        f32x4 c = {};
        c = __builtin_amdgcn_mfma_f32_16x16x32_bf16(ak[mt][0], bq[qg][0], c, 0, 0, 0);
        c = __builtin_amdgcn_mfma_f32_16x16x32_bf16(ak[mt][1], bq[qg][1], c, 0, 0, 0);
        st[qg][mt] = c;
      }

    // V fragments (shared across qg): key chunk for half kh
    bf16x8 av[4];
#pragma unroll
    for (int dt = 0; dt < 4; ++dt)
      av[dt] = *(const bf16x8*)&Vs[(dt * 16 + l16) * 64 + cv];

    // p = exp2(s), then AND with expanded keep-bytes (k = quad*8 + mt*4 + r)
#pragma unroll
    for (int qg = 0; qg < 2; ++qg) {
      const unsigned mx = qg ? mbv1.x : mbv0.x;   // bytes for mt=0 (r=0..3)
      const unsigned my = qg ? mbv1.y : mbv0.y;   // bytes for mt=1 (r=0..3)
      union { unsigned u[4]; bf16x8 v; } pk;
      pk.u[0] = pk_bf16(__builtin_exp2f(st[qg][0][0]), __builtin_exp2f(st[qg][0][1])) & pmexp(mx, 0x01010000u);
      pk.u[1] = pk_bf16(__builtin_exp2f(st[qg][0][2]), __builtin_exp2f(st[qg][0][3])) & pmexp(mx, 0x03030202u);
      pk.u[2] = pk_bf16(__builtin_exp2f(st[qg][1][0]), __builtin_exp2f(st[qg][1][1])) & pmexp(my, 0x01010000u);
      pk.u[3] = pk_bf16(__builtin_exp2f(st[qg][1][2]), __builtin_exp2f(st[qg][1][3])) & pmexp(my, 0x03030202u);
      o_l[qg] = __builtin_amdgcn_mfma_f32_16x16x32_bf16(ones, pk.v, o_l[qg], 0, 0, 0);
#pragma unroll
      for (int dt = 0; dt < 4; ++dt)
        o_acc[qg][dt] = __builtin_amdgcn_mfma_f32_16x16x32_bf16(av[dt], pk.v, o_acc[qg][dt], 0, 0, 0);
    }
  }

  // combine the two key-halves: two passes (ph = qhalf) through a 16KB-resident buffer
#pragma unroll
  for (int ph = 0; ph < 2; ++ph) {
    __syncthreads();
    if (kh == 1 && qhalf == ph) {
#pragma unroll
      for (int qg = 0; qg < 2; ++qg) {
#pragma unroll
        for (int dt = 0; dt < 4; ++dt)
          *(f32x4*)&Cmb[(qg * 16 + l16) * 68 + dt * 16 + quad * 4] = o_acc[qg][dt];
        if (quad == 0) lp[qg * 16 + l16] = o_l[qg][0];
      }
    }
    __syncthreads();
    if (kh == 0 && qhalf == ph) {
#pragma unroll
      for (int qg = 0; qg < 2; ++qg) {
        const float l = o_l[qg][0] + lp[qg * 16 + l16];
        const float inv = 1.0f / l;
        const int R = qt * 64 + qhalf * 32 + qg * 16 + l16;
        unsigned short* Crow = Ctx + (size_t)(b * SN + R) * EN + h * 64;
#pragma unroll
        for (int dt = 0; dt < 4; ++dt) {
          const f32x4 part = *(const f32x4*)&Cmb[(qg * 16 + l16) * 68 + dt * 16 + quad * 4];
          ushort4 wst;
          wst.x = f2bf((o_acc[qg][dt][0] + part[0]) * inv);
          wst.y = f2bf((o_acc[qg][dt][1] + part[1]) * inv);
          wst.z = f2bf((o_acc[qg][dt][2] + part[2]) * inv);
          wst.w = f2bf((o_acc[qg][dt][3] + part[3]) * inv);
          *(ushort4*)&Crow[dt * 16 + quad * 4] = wst;
        }
      }
    }
  }
}

// ---------------------------------------------------------------- LayerNorm: one wave per row, float4
__global__ __launch_bounds__(256) void ln_kernel(const float* __restrict__ X,
                                                 float* __restrict__ Y) {
  const int wave = threadIdx.x >> 6, lane = threadIdx.x & 63;
  const int row = blockIdx.x * 4 + wave;
  const float* xr = X + (size_t)row * EN;
  float4 v[3];
  float s = 0.f, ss = 0.f;
#pragma unroll
  for (int i = 0; i < 3; ++i) {
    v[i] = ((const float4*)xr)[lane + i * 64];
    s  += v[i].x + v[i].y + v[i].z + v[i].w;
    ss += v[i].x * v[i].x + v[i].y * v[i].y + v[i].z * v[i].z + v[i].w * v[i].w;
  }
#pragma unroll
  for (int off = 1; off < 64; off <<= 1) {
    s += __shfl_xor(s, off, 64);
    ss += __shfl_xor(ss, off, 64);
  }
  const float mean = s * (1.0f / EN);
  const float var = ss * (1.0f / EN) - mean * mean;
  const float rstd = rsqrtf(var + 1e-5f);
  float* yr = Y + (size_t)row * EN;
#pragma unroll
  for (int i = 0; i < 3; ++i) {
    float4 o;
    o.x = (v[i].x - mean) * rstd;
    o.y = (v[i].y - mean) * rstd;
    o.z = (v[i].z - mean) * rstd;
    o.w = (v[i].w - mean) * rstd;
    ((float4*)yr)[lane + i * 64] = o;
  }
}

// ---------------------------------------------------------------- launch
extern "C" void kernel_launch(void* const* d_in, const int* in_sizes, int n_in,
                              void* d_out, int out_size, void* d_ws, size_t ws_size,
                              hipStream_t stream) {
  (void)in_sizes; (void)n_in; (void)out_size; (void)ws_size;
  const float* query = (const float*)d_in[0];
  const float* key_i = (const float*)d_in[1];
  const float* value = (const float*)d_in[2];
  const int*   mask  = (const int*)d_in[3];
  const float* Wq = (const float*)d_in[4];
  const float* Wk = (const float*)d_in[5];
  const float* Wv = (const float*)d_in[6];
  const float* Wo = (const float*)d_in[7];

  const size_t NBIG = (size_t)MROWS * EN;  // 6291456
  const size_t NW   = (size_t)EN * EN;     // 589824

  unsigned short* Xq16 = (unsigned short*)d_ws;   // X bank: q,k,v contiguous
  unsigned short* Wq16 = Xq16 + 3 * NBIG;         // W bank: wq,wk,wv,wo contiguous
  unsigned short* Wo16 = Wq16 + 3 * NW;
  unsigned short* Q16  = Wo16 + NW;               // out bank: Q,K,Vt contiguous
  unsigned short* K16  = Q16 + NBIG;
  unsigned short* Vt16 = K16 + NBIG;
  unsigned short* Ctx16 = Vt16 + NBIG;
  float* OutF = (float*)(Ctx16 + NBIG);
  // keep-byte mask table (16.8 MB) aliases OutF (25.2 MB): attn reads it BEFORE
  // gemm_out writes OutF (stream-ordered).
  unsigned char* Mbytes = (unsigned char*)OutF;

  cvt_mask<<<NCVTB + NMASKB, 256, 0, stream>>>(query, key_i, value, Wq, Wk, Wv, Wo,
                                               Xq16, mask, (unsigned*)Mbytes);

  // Q scale: 1/sqrt(dk) * log2(e) so softmax is a bare exp2
  gemm_qkv<<<dim3(MROWS / 128, EN / 128, 3), 256, 0, stream>>>(
      Xq16, Wq16, Q16, 0.125f * 1.44269504088896f);

  attn_kernel<<<dim3((SN / 64) * BATCH * HN), 256, 0, stream>>>(
      Q16, K16, Vt16, Mbytes, Ctx16);

  gemm_out<<<dim3(MROWS / 128, EN / 128), 256, 0, stream>>>(Ctx16, Wo16, OutF, query);

  ln_kernel<<<MROWS / 4, 256, 0, stream>>>(OutF, (float*)d_out);
}

// Round 12
// 359.780 us; speedup vs baseline: 1.0196x; 1.0196x over previous
//
#include <hip/hip_runtime.h>
#include <stdint.h>
#include <stddef.h>

#define HN   12
#define SN   2048
#define EN   768
#define DKN  64
#define BATCH 4
#define MROWS 8192   // BATCH*SN

typedef short bf16x8 __attribute__((ext_vector_type(8)));
typedef float f32x4 __attribute__((ext_vector_type(4)));

__device__ __forceinline__ unsigned short f2bf(float f) {
  union { float f; unsigned u; } x; x.f = f;
  unsigned r = x.u + 0x7fffu + ((x.u >> 16) & 1u);
  return (unsigned short)(r >> 16);
}

#if __has_builtin(__builtin_amdgcn_cvt_pk_bf16_f32)
typedef __bf16 bf16v2 __attribute__((ext_vector_type(2)));
__device__ __forceinline__ unsigned pk_bf16(float a, float b) {
  union { bf16v2 v; unsigned u; } c;
  c.v = __builtin_amdgcn_cvt_pk_bf16_f32(a, b);
  return c.u;
}
#else
__device__ __forceinline__ unsigned pk_bf16(float a, float b) {
  return (unsigned)f2bf(a) | ((unsigned)f2bf(b) << 16);
}
#endif

// byte-pair expand via v_perm: sel 0x01010000 -> [b0 b0 b1 b1], sel 0x03030202 -> [b2 b2 b3 b3].
#if __has_builtin(__builtin_amdgcn_perm)
__device__ __forceinline__ unsigned pmexp(unsigned m, unsigned sel) {
  return __builtin_amdgcn_perm(m, m, sel);
}
#else
__device__ __forceinline__ unsigned pmexp(unsigned m, unsigned sel) {
  const unsigned b0 = (m >> (8 * (sel & 3))) & 0xFFu;
  const unsigned b1 = (m >> (8 * ((sel >> 16) & 3))) & 0xFFu;
  return (b0 ? 0xFFFFu : 0u) | (b1 ? 0xFFFF0000u : 0u);
}
#endif

#define GLD_LDS16(gptr, lptr) \
  __builtin_amdgcn_global_load_lds((const __attribute__((address_space(1))) void*)(gptr), \
                                   (__attribute__((address_space(3))) void*)(lptr), 16, 0, 0)

// ---------------------------------------------------------------- fused f32->bf16 + mask->keep-bytes
#define NBIG4 1572864   // NBIG/4
#define NW4   147456    // NW/4
#define NCVTB 20736     // (3*NBIG4 + 4*NW4)/256
#define NMASKB 16384    // B*S*S/4/256
__global__ __launch_bounds__(256) void cvt_mask(const float* __restrict__ q,
                                                const float* __restrict__ k,
                                                const float* __restrict__ v,
                                                const float* __restrict__ wq,
                                                const float* __restrict__ wk,
                                                const float* __restrict__ wv,
                                                const float* __restrict__ wo,
                                                unsigned short* __restrict__ dst,
                                                const int* __restrict__ mask,
                                                unsigned* __restrict__ mout) {
  if (blockIdx.x < NCVTB) {
    const int i = blockIdx.x * 256 + threadIdx.x;
    const float* src;
    int off;
    if (i < 3 * NBIG4) {
      const int r = i / NBIG4;
      src = (r == 0) ? q : (r == 1) ? k : v;
      off = i - r * NBIG4;
    } else {
      const int j = i - 3 * NBIG4;
      const int r = j / NW4;
      src = (r == 0) ? wq : (r == 1) ? wk : (r == 2) ? wv : wo;
      off = j - r * NW4;
    }
    float4 val = ((const float4*)src)[off];
    ushort4 o;
    o.x = f2bf(val.x); o.y = f2bf(val.y); o.z = f2bf(val.z); o.w = f2bf(val.w);
    ((ushort4*)dst)[i] = o;
  } else {
    // keep = (mask==0) -> 0xFF ; exclude -> 0x00.  u32 packs 4 consecutive keys.
    const size_t i = (size_t)(blockIdx.x - NCVTB) * 256 + threadIdx.x;
    const int4 m = ((const int4*)mask)[i];
    unsigned o = (m.x ? 0u : 0xFFu) | (m.y ? 0u : 0xFF00u) |
                 (m.z ? 0u : 0xFF0000u) | (m.w ? 0u : 0xFF000000u);
    mout[i] = o;
  }
}

// ---------------------------------------------------------------- batched QKV GEMM (BK=64, XOR-swizzled)
// z=0: Q (scaled, [B,H,S,DK]); z=1: K ([B,H,S,DK]); z=2: V transposed ([B,H,DK,S])
// BK 32->64: 12 K-steps instead of 24 -> HALF the barrier drains (the m97-family loop's
// dominant stall). Staging uses the attn kernel's proven XOR swizzle (phys chunk =
// logical chunk ^ (row&7)) so the [128][64] fragment reads are ~2-way instead of the
// 16-way conflict a linear BK=64 layout would have (BK=32 linear was already 8-way).
// LDS 32KB (m132's BK=128 regression was the 64KB occupancy cliff; 32KB keeps 5 blocks).
__global__ __launch_bounds__(256) void gemm_qkv(const unsigned short* __restrict__ Xb,
                                                const unsigned short* __restrict__ Wb,
                                                unsigned short* __restrict__ Ob,
                                                float qscale) {
  __shared__ unsigned short As[128 * 64];
  __shared__ unsigned short Bs[128 * 64];
  const int tid  = threadIdx.x;
  const int wave = tid >> 6;
  const int lane = tid & 63;
  const int quad = lane >> 4;
  const int l16  = lane & 15;
  const int bm = blockIdx.x;
  const int bn = blockIdx.y;
  const int z  = blockIdx.z;
  const int wm = wave & 1;
  const int wn = wave >> 1;

  const unsigned short* X = Xb + (size_t)z * MROWS * EN;
  const unsigned short* W = Wb + (size_t)z * EN * EN;
  unsigned short* O = Ob + (size_t)z * MROWS * EN;

  f32x4 acc[4][4] = {};
  const int srow  = lane >> 3;                 // 0..7 (row within an 8-row gld_lds group)
  const int swsrc = ((lane & 7) ^ srow) * 8;   // XOR-swizzled source col chunk
  const int cswz  = l16 & 7;                   // read-side XOR key (= row & 7)

  for (int bk = 0; bk < 12; ++bk) {
    __syncthreads();
#pragma unroll
    for (int r = 0; r < 4; ++r) {
      const int rb = r * 32 + wave * 8;
      GLD_LDS16(X + (size_t)(bm * 128 + rb + srow) * EN + bk * 64 + swsrc, As + rb * 64);
      GLD_LDS16(W + (size_t)(bn * 128 + rb + srow) * EN + bk * 64 + swsrc, Bs + rb * 64);
    }
    __syncthreads();

#pragma unroll
    for (int kc = 0; kc < 2; ++kc) {
      bf16x8 af[4], bfr[4];
#pragma unroll
      for (int mt = 0; mt < 4; ++mt)
        af[mt] = *(const bf16x8*)&As[(wm * 64 + mt * 16 + l16) * 64 + ((kc * 4 + quad) ^ cswz) * 8];
#pragma unroll
      for (int nt = 0; nt < 4; ++nt)
        bfr[nt] = *(const bf16x8*)&Bs[(wn * 64 + nt * 16 + l16) * 64 + ((kc * 4 + quad) ^ cswz) * 8];
#pragma unroll
      for (int mt = 0; mt < 4; ++mt)
#pragma unroll
        for (int nt = 0; nt < 4; ++nt)
          acc[mt][nt] = __builtin_amdgcn_mfma_f32_16x16x32_bf16(af[mt], bfr[nt], acc[mt][nt], 0, 0, 0);
    }
  }

  const int m0 = bm * 128 + wm * 64;
  const int n0 = bn * 128 + wn * 64;
  const float scale = (z == 0) ? qscale : 1.0f;

  if (z < 2) {
#pragma unroll
    for (int mt = 0; mt < 4; ++mt) {
#pragma unroll
      for (int nt = 0; nt < 4; ++nt) {
        const int n = n0 + nt * 16 + l16;
        const int h = n >> 6, d = n & 63;
#pragma unroll
        for (int r = 0; r < 4; ++r) {
          const int m = m0 + mt * 16 + quad * 4 + r;
          const int b = m >> 11, s = m & 2047;
          O[((size_t)(b * HN + h) * SN + s) * DKN + d] = f2bf(acc[mt][nt][r] * scale);
        }
      }
    }
  } else {
#pragma unroll
    for (int mt = 0; mt < 4; ++mt) {
#pragma unroll
      for (int nt = 0; nt < 4; ++nt) {
        const int n = n0 + nt * 16 + l16;
        const int h = n >> 6, d = n & 63;
        const int m = m0 + mt * 16 + quad * 4;
        const int b = m >> 11, s = m & 2047;
        ushort4 pk;
        pk.x = f2bf(acc[mt][nt][0]);
        pk.y = f2bf(acc[mt][nt][1]);
        pk.z = f2bf(acc[mt][nt][2]);
        pk.w = f2bf(acc[mt][nt][3]);
        *(ushort4*)&O[((size_t)(b * HN + h) * DKN + d) * SN + s] = pk;
      }
    }
  }
}

// ---------------------------------------------------------------- GEMM  C = X @ W^T + residual (BK=64, swizzled)
__global__ __launch_bounds__(256) void gemm_out(const unsigned short* __restrict__ X,
                                                const unsigned short* __restrict__ W,
                                                float* __restrict__ O,
                                                const float* __restrict__ residual) {
  __shared__ unsigned short As[128 * 64];
  __shared__ unsigned short Bs[128 * 64];
  const int tid  = threadIdx.x;
  const int wave = tid >> 6;
  const int lane = tid & 63;
  const int quad = lane >> 4;
  const int l16  = lane & 15;
  const int bm = blockIdx.x;
  const int bn = blockIdx.y;
  const int wm = wave & 1;
  const int wn = wave >> 1;

  f32x4 acc[4][4] = {};
  const int srow  = lane >> 3;
  const int swsrc = ((lane & 7) ^ srow) * 8;
  const int cswz  = l16 & 7;

  for (int bk = 0; bk < 12; ++bk) {
    __syncthreads();
#pragma unroll
    for (int r = 0; r < 4; ++r) {
      const int rb = r * 32 + wave * 8;
      GLD_LDS16(X + (size_t)(bm * 128 + rb + srow) * EN + bk * 64 + swsrc, As + rb * 64);
      GLD_LDS16(W + (size_t)(bn * 128 + rb + srow) * EN + bk * 64 + swsrc, Bs + rb * 64);
    }
    __syncthreads();

#pragma unroll
    for (int kc = 0; kc < 2; ++kc) {
      bf16x8 af[4], bfr[4];
#pragma unroll
      for (int mt = 0; mt < 4; ++mt)
        af[mt] = *(const bf16x8*)&As[(wm * 64 + mt * 16 + l16) * 64 + ((kc * 4 + quad) ^ cswz) * 8];
#pragma unroll
      for (int nt = 0; nt < 4; ++nt)
        bfr[nt] = *(const bf16x8*)&Bs[(wn * 64 + nt * 16 + l16) * 64 + ((kc * 4 + quad) ^ cswz) * 8];
#pragma unroll
      for (int mt = 0; mt < 4; ++mt)
#pragma unroll
        for (int nt = 0; nt < 4; ++nt)
          acc[mt][nt] = __builtin_amdgcn_mfma_f32_16x16x32_bf16(af[mt], bfr[nt], acc[mt][nt], 0, 0, 0);
    }
  }

  const int m0 = bm * 128 + wm * 64;
  const int n0 = bn * 128 + wn * 64;
#pragma unroll
  for (int mt = 0; mt < 4; ++mt) {
#pragma unroll
    for (int nt = 0; nt < 4; ++nt) {
      const int n = n0 + nt * 16 + l16;
#pragma unroll
      for (int r = 0; r < 4; ++r) {
        const int m = m0 + mt * 16 + quad * 4 + r;
        const size_t idx = (size_t)m * EN + n;
        O[idx] = acc[mt][nt][r] + residual[idx];
      }
    }
  }
}

// ---------------------------------------------------------------- flash attention (key-split waves)
// R11 kernel exactly: R4 math + XCD swizzle (FETCH 115->58MB) + 16KB LDS two-pass combine.
__global__ __launch_bounds__(256, 4) void attn_kernel(const unsigned short* __restrict__ Q,
                                                      const unsigned short* __restrict__ K,
                                                      const unsigned short* __restrict__ Vt,
                                                      const unsigned char* __restrict__ Mb,
                                                      unsigned short* __restrict__ Ctx) {
  __shared__ __align__(16) unsigned char LDSBUF[16384];   // staging (16KB) / combine (8704+128B)
  unsigned short* Ks = (unsigned short*)LDSBUF;           // [64][64] perm-key x d
  unsigned short* Vs = (unsigned short*)(LDSBUF + 8192);  // [64][64] d x key
  float* Cmb = (float*)LDSBUF;                            // [32][68] q x d, padded (combine)
  float* lp  = (float*)(LDSBUF + 8704);                   // [2][16] l partials (combine)

  const int tid  = threadIdx.x;
  const int wave = tid >> 6, lane = tid & 63;
  const int quad = lane >> 4, l16 = lane & 15;
  const int qhalf = wave >> 1, kh = wave & 1;

  // XCD-aware swizzle: 1536 blocks, 8 XCDs, 192 per XCD; qt fast within a head.
  const int wg = blockIdx.x;
  const int sw = (wg & 7) * 192 + (wg >> 3);
  const int qt = sw & 31;
  const int bh = sw >> 5;
  const int b = bh / HN, h = bh - b * HN;

  const unsigned short* Qp = Q + (size_t)bh * SN * DKN;
  const unsigned short* Kp = K + (size_t)bh * SN * DKN;
  const unsigned short* Vp = Vt + (size_t)bh * DKN * SN;

  const int srow = lane >> 3;
  const int schk = lane & 7;
  const int swsrc = (schk ^ srow) * 8;
  const int c0 = (quad ^ (l16 & 7)) * 8;                    // K frag chunks (d)
  const int cv = (((kh << 2) + quad) ^ (l16 & 7)) * 8;      // V frag chunk (key half kh)

  // K staging: dest physical row (within half) pw holds logical key yk
  const int pw = wave * 8 + srow;
  const int yk = (((pw >> 2) & 3) << 3) + ((pw >> 4) << 2) + (pw & 3);

  // Q B-fragments for this wave's 32 q-rows (2 groups of 16), hoisted
  bf16x8 bq[2][2];
#pragma unroll
  for (int qg = 0; qg < 2; ++qg) {
    const int R = qt * 64 + qhalf * 32 + qg * 16 + l16;
    bq[qg][0] = *(const bf16x8*)(Qp + (size_t)R * DKN + quad * 8);
    bq[qg][1] = *(const bf16x8*)(Qp + (size_t)R * DKN + 32 + quad * 8);
  }

  // keep-byte mask pointers: row*SN + kt*64 + kh*32 + quad*8 (8B-aligned); qg=1 at +16 rows
  const unsigned char* Ml0 =
      Mb + ((size_t)b * SN + (size_t)(qt * 64 + qhalf * 32 + l16)) * SN + kh * 32 + quad * 8;
  const unsigned char* Ml1 = Ml0 + (size_t)16 * SN;

  f32x4 o_acc[2][4] = {};
  f32x4 o_l[2] = {};
  bf16x8 ones;
#pragma unroll
  for (int i = 0; i < 8; ++i) ones[i] = (short)0x3F80;  // bf16 1.0

  for (int kt = 0; kt < 32; ++kt) {
    __syncthreads();
    GLD_LDS16(Kp + (size_t)(kt * 64 + yk) * DKN + swsrc,              Ks + (wave * 8) * 64);
    GLD_LDS16(Kp + (size_t)(kt * 64 + 32 + yk) * DKN + swsrc,         Ks + (32 + wave * 8) * 64);
    GLD_LDS16(Vp + (size_t)(wave * 8 + srow) * SN + kt * 64 + swsrc,      Vs + (wave * 8) * 64);
    GLD_LDS16(Vp + (size_t)(32 + wave * 8 + srow) * SN + kt * 64 + swsrc, Vs + (32 + wave * 8) * 64);
    const uint2 mbv0 = *(const uint2*)(Ml0 + (size_t)kt * 64);
    const uint2 mbv1 = *(const uint2*)(Ml1 + (size_t)kt * 64);
    __syncthreads();

    // K fragments: this wave's key-half only
    bf16x8 ak[2][2];
#pragma unroll
    for (int mt = 0; mt < 2; ++mt) {
      const int base = (kh * 32 + mt * 16 + l16) * 64;
      ak[mt][0] = *(const bf16x8*)&Ks[base + c0];
      ak[mt][1] = *(const bf16x8*)&Ks[base + (c0 ^ 32)];
    }

    // S^T = K x Q^T for 32q x 32k
    f32x4 st[2][2];
#pragma unroll
    for (int qg = 0; qg < 2; ++qg)
#pragma unroll
      for (int mt = 0; mt < 2; ++mt) {
        f32x4 c = {};
        c = __builtin_amdgcn_mfma_f32_16x16x32_bf16(ak[mt][0], bq[qg][0], c, 0, 0, 0);
        c = __builtin_amdgcn_mfma_f32_16x16x32_bf16(ak[mt][1], bq[qg][1], c, 0, 0, 0);
        st[qg][mt] = c;
      }

    // V fragments (shared across qg): key chunk for half kh
    bf16x8 av[4];
#pragma unroll
    for (int dt = 0; dt < 4; ++dt)
      av[dt] = *(const bf16x8*)&Vs[(dt * 16 + l16) * 64 + cv];

    // p = exp2(s), then AND with expanded keep-bytes (k = quad*8 + mt*4 + r)
#pragma unroll
    for (int qg = 0; qg < 2; ++qg) {
      const unsigned mx = qg ? mbv1.x : mbv0.x;   // bytes for mt=0 (r=0..3)
      const unsigned my = qg ? mbv1.y : mbv0.y;   // bytes for mt=1 (r=0..3)
      union { unsigned u[4]; bf16x8 v; } pk;
      pk.u[0] = pk_bf16(__builtin_exp2f(st[qg][0][0]), __builtin_exp2f(st[qg][0][1])) & pmexp(mx, 0x01010000u);
      pk.u[1] = pk_bf16(__builtin_exp2f(st[qg][0][2]), __builtin_exp2f(st[qg][0][3])) & pmexp(mx, 0x03030202u);
      pk.u[2] = pk_bf16(__builtin_exp2f(st[qg][1][0]), __builtin_exp2f(st[qg][1][1])) & pmexp(my, 0x01010000u);
      pk.u[3] = pk_bf16(__builtin_exp2f(st[qg][1][2]), __builtin_exp2f(st[qg][1][3])) & pmexp(my, 0x03030202u);
      o_l[qg] = __builtin_amdgcn_mfma_f32_16x16x32_bf16(ones, pk.v, o_l[qg], 0, 0, 0);
#pragma unroll
      for (int dt = 0; dt < 4; ++dt)
        o_acc[qg][dt] = __builtin_amdgcn_mfma_f32_16x16x32_bf16(av[dt], pk.v, o_acc[qg][dt], 0, 0, 0);
    }
  }

  // combine the two key-halves: two passes (ph = qhalf) through a 16KB-resident buffer
#pragma unroll
  for (int ph = 0; ph < 2; ++ph) {
    __syncthreads();
    if (kh == 1 && qhalf == ph) {
#pragma unroll
      for (int qg = 0; qg < 2; ++qg) {
#pragma unroll
        for (int dt = 0; dt < 4; ++dt)
          *(f32x4*)&Cmb[(qg * 16 + l16) * 68 + dt * 16 + quad * 4] = o_acc[qg][dt];
        if (quad == 0) lp[qg * 16 + l16] = o_l[qg][0];
      }
    }
    __syncthreads();
    if (kh == 0 && qhalf == ph) {
#pragma unroll
      for (int qg = 0; qg < 2; ++qg) {
        const float l = o_l[qg][0] + lp[qg * 16 + l16];
        const float inv = 1.0f / l;
        const int R = qt * 64 + qhalf * 32 + qg * 16 + l16;
        unsigned short* Crow = Ctx + (size_t)(b * SN + R) * EN + h * 64;
#pragma unroll
        for (int dt = 0; dt < 4; ++dt) {
          const f32x4 part = *(const f32x4*)&Cmb[(qg * 16 + l16) * 68 + dt * 16 + quad * 4];
          ushort4 wst;
          wst.x = f2bf((o_acc[qg][dt][0] + part[0]) * inv);
          wst.y = f2bf((o_acc[qg][dt][1] + part[1]) * inv);
          wst.z = f2bf((o_acc[qg][dt][2] + part[2]) * inv);
          wst.w = f2bf((o_acc[qg][dt][3] + part[3]) * inv);
          *(ushort4*)&Crow[dt * 16 + quad * 4] = wst;
        }
      }
    }
  }
}

// ---------------------------------------------------------------- LayerNorm: one wave per row, float4
__global__ __launch_bounds__(256) void ln_kernel(const float* __restrict__ X,
                                                 float* __restrict__ Y) {
  const int wave = threadIdx.x >> 6, lane = threadIdx.x & 63;
  const int row = blockIdx.x * 4 + wave;
  const float* xr = X + (size_t)row * EN;
  float4 v[3];
  float s = 0.f, ss = 0.f;
#pragma unroll
  for (int i = 0; i < 3; ++i) {
    v[i] = ((const float4*)xr)[lane + i * 64];
    s  += v[i].x + v[i].y + v[i].z + v[i].w;
    ss += v[i].x * v[i].x + v[i].y * v[i].y + v[i].z * v[i].z + v[i].w * v[i].w;
  }
#pragma unroll
  for (int off = 1; off < 64; off <<= 1) {
    s += __shfl_xor(s, off, 64);
    ss += __shfl_xor(ss, off, 64);
  }
  const float mean = s * (1.0f / EN);
  const float var = ss * (1.0f / EN) - mean * mean;
  const float rstd = rsqrtf(var + 1e-5f);
  float* yr = Y + (size_t)row * EN;
#pragma unroll
  for (int i = 0; i < 3; ++i) {
    float4 o;
    o.x = (v[i].x - mean) * rstd;
    o.y = (v[i].y - mean) * rstd;
    o.z = (v[i].z - mean) * rstd;
    o.w = (v[i].w - mean) * rstd;
    ((float4*)yr)[lane + i * 64] = o;
  }
}

// ---------------------------------------------------------------- launch
extern "C" void kernel_launch(void* const* d_in, const int* in_sizes, int n_in,
                              void* d_out, int out_size, void* d_ws, size_t ws_size,
                              hipStream_t stream) {
  (void)in_sizes; (void)n_in; (void)out_size; (void)ws_size;
  const float* query = (const float*)d_in[0];
  const float* key_i = (const float*)d_in[1];
  const float* value = (const float*)d_in[2];
  const int*   mask  = (const int*)d_in[3];
  const float* Wq = (const float*)d_in[4];
  const float* Wk = (const float*)d_in[5];
  const float* Wv = (const float*)d_in[6];
  const float* Wo = (const float*)d_in[7];

  const size_t NBIG = (size_t)MROWS * EN;  // 6291456
  const size_t NW   = (size_t)EN * EN;     // 589824

  unsigned short* Xq16 = (unsigned short*)d_ws;   // X bank: q,k,v contiguous
  unsigned short* Wq16 = Xq16 + 3 * NBIG;         // W bank: wq,wk,wv,wo contiguous
  unsigned short* Wo16 = Wq16 + 3 * NW;
  unsigned short* Q16  = Wo16 + NW;               // out bank: Q,K,Vt contiguous
  unsigned short* K16  = Q16 + NBIG;
  unsigned short* Vt16 = K16 + NBIG;
  unsigned short* Ctx16 = Vt16 + NBIG;
  float* OutF = (float*)(Ctx16 + NBIG);
  // keep-byte mask table (16.8 MB) aliases OutF (25.2 MB): attn reads it BEFORE
  // gemm_out writes OutF (stream-ordered).
  unsigned char* Mbytes = (unsigned char*)OutF;

  cvt_mask<<<NCVTB + NMASKB, 256, 0, stream>>>(query, key_i, value, Wq, Wk, Wv, Wo,
                                               Xq16, mask, (unsigned*)Mbytes);

  // Q scale: 1/sqrt(dk) * log2(e) so softmax is a bare exp2
  gemm_qkv<<<dim3(MROWS / 128, EN / 128, 3), 256, 0, stream>>>(
      Xq16, Wq16, Q16, 0.125f * 1.44269504088896f);

  attn_kernel<<<dim3((SN / 64) * BATCH * HN), 256, 0, stream>>>(
      Q16, K16, Vt16, Mbytes, Ctx16);

  gemm_out<<<dim3(MROWS / 128, EN / 128), 256, 0, stream>>>(Ctx16, Wo16, OutF, query);

  ln_kernel<<<MROWS / 4, 256, 0, stream>>>(OutF, (float*)d_out);
}